// Round 2
// baseline (863.749 us; speedup 1.0000x reference)
//
#include <hip/hip_runtime.h>

#define BATCH 4
#define SEQ   2048
#define DIM   2048
#define NH    16
#define HD    128

typedef __bf16 bf16x8 __attribute__((ext_vector_type(8)));
typedef float  f32x4  __attribute__((ext_vector_type(4)));

__device__ __forceinline__ unsigned short f2bf(float f) {
  unsigned int u = __builtin_bit_cast(unsigned int, f);
  u += 0x7fffu + ((u >> 16) & 1u);          // RNE
  return (unsigned short)(u >> 16);
}

// async global->LDS, 16B per lane; LDS dest must be wave-uniform-base + lane*16
__device__ __forceinline__ void async16(void* lds, const void* g) {
  __builtin_amdgcn_global_load_lds(
      (const __attribute__((address_space(1))) unsigned int*)g,
      (__attribute__((address_space(3))) unsigned int*)lds, 16, 0, 0);
}

// ---------------------------------------------------------------- one cast dispatch for x + all 4 weights
__global__ __launch_bounds__(256) void cast_all_kernel(
    const float* __restrict__ x,
    const float* __restrict__ w0, const float* __restrict__ w1,
    const float* __restrict__ w2, const float* __restrict__ w3,
    unsigned short* __restrict__ dst) {
  int i = blockIdx.x * 256 + threadIdx.x;
  const float* s;
  int loc;
  if (i < (1 << 22)) { s = x; loc = i; }
  else {
    int k = i - (1 << 22);
    int sel = k >> 20; loc = k & 0xfffff;
    s = sel == 0 ? w0 : sel == 1 ? w1 : sel == 2 ? w2 : w3;
  }
  float4 v = ((const float4*)s)[loc];
  ushort4 o;
  o.x = f2bf(v.x); o.y = f2bf(v.y); o.z = f2bf(v.z); o.w = f2bf(v.w);
  ((ushort4*)dst)[i] = o;
}

// ---------------------------------------------------------------- fused QKV GEMM + RoPE + V-transpose
// (unchanged this round; 8-phase port pending validation of gemm_out's new core)
__global__ __launch_bounds__(256) void gemm_qkv(
    const unsigned short* __restrict__ A,    // xb (8192 x 2048) bf16
    const unsigned short* __restrict__ Wq,
    const unsigned short* __restrict__ Wk,
    const unsigned short* __restrict__ Wv,
    unsigned short* __restrict__ Qo,
    unsigned short* __restrict__ Ko,
    unsigned short* __restrict__ Vto) {
  __shared__ unsigned short As[128 * 32];
  __shared__ unsigned short Bs[128 * 32];
  __shared__ float ep[32 * 132];
  const int tid = threadIdx.x;
  const int lane = tid & 63, wv = tid >> 6;
  const int q15 = lane & 15, quad = lane >> 4;
  const int wm = wv >> 1, wn = wv & 1;
  const int gx = blockIdx.x;
  const int sel = gx >> 4, h = gx & 15;
  const int m0 = blockIdx.y * 128;
  const unsigned short* Bw =
      (sel == 0 ? Wq : (sel == 1 ? Wk : Wv)) + (size_t)h * 128 * DIM;

  f32x4 acc[4][4] = {};

  for (int kt = 0; kt < DIM; kt += 32) {
    __syncthreads();
#pragma unroll
    for (int i = 0; i < 2; ++i) {
      int l = i * 256 + tid;
      int r = l >> 2, s = l & 3;
      int c = (s - (r >> 1)) & 3;
      async16(&As[l * 8], A + (size_t)(m0 + r) * DIM + kt + c * 8);
    }
#pragma unroll
    for (int i = 0; i < 2; ++i) {
      int l = i * 256 + tid;
      int r = l >> 2, s = l & 3;
      int c = (s - (r >> 1)) & 3;
      async16(&Bs[l * 8], Bw + (size_t)r * DIM + kt + c * 8);
    }
    __syncthreads();

    bf16x8 af[4], bf[4];
#pragma unroll
    for (int mf = 0; mf < 4; ++mf) {
      int r = wm * 64 + mf * 16 + q15;
      int sl = r * 4 + ((quad + (r >> 1)) & 3);
      af[mf] = *(const bf16x8*)&As[sl * 8];
    }
#pragma unroll
    for (int nf = 0; nf < 4; ++nf) {
      int r = wn * 64 + nf * 16 + q15;
      int sl = r * 4 + ((quad + (r >> 1)) & 3);
      bf[nf] = *(const bf16x8*)&Bs[sl * 8];
    }
#pragma unroll
    for (int mf = 0; mf < 4; ++mf)
#pragma unroll
      for (int nf = 0; nf < 4; ++nf)
        acc[mf][nf] = __builtin_amdgcn_mfma_f32_16x16x32_bf16(af[mf], bf[nf], acc[mf][nf], 0, 0, 0);
  }

  const int b = m0 >> 11;
  const int s0 = m0 & (SEQ - 1);
  const int bh = b * NH + h;
  const float CS = 0.12751744f;

  float invf[2][8];
  if (sel < 2) {
#pragma unroll
    for (int oi = 0; oi < 2; ++oi) {
      int oc = ((oi * 256 + tid) & 15) * 8;
#pragma unroll
      for (int j = 0; j < 8; ++j)
        invf[oi][j] = exp2f(-(float)((oc & 63) + j) * 0.20762050593046932f);
    }
  }

  for (int c = 0; c < 4; ++c) {
    __syncthreads();
    if (wm == (c >> 1)) {
      int mfb = (c & 1) * 2;
#pragma unroll
      for (int mi = 0; mi < 2; ++mi) {
        int mf = mfb + mi;
        int rr0 = mf * 16 + quad * 4 - (c & 1) * 32;
#pragma unroll
        for (int nf = 0; nf < 4; ++nf) {
          int col = wn * 64 + nf * 16 + q15;
#pragma unroll
          for (int r = 0; r < 4; ++r)
            ep[(rr0 + r) * 132 + col] = acc[mf][nf][r];
        }
      }
    }
    __syncthreads();
#pragma unroll
    for (int oi = 0; oi < 2; ++oi) {
      int o = oi * 256 + tid;
      if (sel < 2) {
        int rr = o >> 4, oc = (o & 15) * 8;
        int s = s0 + c * 32 + rr;
        float sf = (float)s;
        float4 a0 = *(const float4*)&ep[rr * 132 + oc];
        float4 a1 = *(const float4*)&ep[rr * 132 + oc + 4];
        float4 b0 = *(const float4*)&ep[rr * 132 + (oc ^ 64)];
        float4 b1 = *(const float4*)&ep[rr * 132 + (oc ^ 64) + 4];
        float av[8] = {a0.x, a0.y, a0.z, a0.w, a1.x, a1.y, a1.z, a1.w};
        float bv[8] = {b0.x, b0.y, b0.z, b0.w, b1.x, b1.y, b1.z, b1.w};
        float sgn = (oc & 64) ? 1.f : -1.f;
        float scl = (sel == 0) ? CS : 1.0f;
        unsigned short u[8];
#pragma unroll
        for (int j = 0; j < 8; ++j) {
          float ang = sf * invf[oi][j];
          float cc = __cosf(ang), ss = __sinf(ang);
          u[j] = f2bf((av[j] * cc + sgn * bv[j] * ss) * scl);
        }
        unsigned short* dst = (sel == 0 ? Qo : Ko) + ((size_t)bh * SEQ + s) * HD + oc;
        *(uint4*)dst = *(uint4*)u;
      } else {
        int hd = o & 127, so8 = (o >> 7) * 8;
        unsigned short u[8];
#pragma unroll
        for (int k = 0; k < 8; ++k)
          u[k] = f2bf(ep[(so8 + k) * 132 + hd]);
        *(uint4*)(Vto + ((size_t)bh * HD + hd) * SEQ + (s0 + c * 32 + so8)) = *(uint4*)u;
      }
    }
  }
}

// ---------------------------------------------------------------- O-projection GEMM, 256x256 deep-pipelined (T2+T3+T4+T5)
// 512 thr (8 waves, 2M x 4N), BK=64, 2 LDS K-tile buffers (128 KB dynamic).
// Per K-tile T: 4 phases (C-quadrants), each stages one 128x64 half-tile
// (2 x global_load_lds dwordx4/thread) for tiles T+1 (B halves @ P0/P1 -> buf^1)
// and T+2 (A halves @ P2/P3 -> buf). Counted s_waitcnt vmcnt(4) at each P3
// guarantees tile T+1 resident (A halves were staged at T-1:P2/P3). Per-phase
// lgkmcnt(0) + double s_barrier guarantees every wave's ds_reads of a region
// drain before any wave issues the stage that overwrites it.
// st_16x32 LDS swizzle (chunk ^= (row>>2 & 1)<<1) applied on the pre-swizzled
// global source (gload_lds dest must stay linear) and on the ds_read address.
#define STAGE8(buf, op, half, kt)                                               \
  do {                                                                          \
    const unsigned short* Gp = (op) ? Bw : A;                                   \
    const int rb = ((op) ? n0 : m0) + (half) * 128;                             \
    unsigned short* hb = sm + ((((buf) << 1) | (op)) * 2 + (half)) * 8192;      \
    _Pragma("unroll")                                                           \
    for (int jj = 0; jj < 2; ++jj) {                                            \
      int l = jj * 512 + tid;                                                   \
      int rr = l >> 3, cc = l & 7;                                              \
      int cs = cc ^ (((rr >> 2) & 1) << 1);                                     \
      async16(&hb[l * 8], Gp + (size_t)(rb + rr) * DIM + (kt) * 64 + cs * 8);   \
    }                                                                           \
  } while (0)

#define RDA8(dst, buf, mf, ks)                                                  \
  do {                                                                          \
    int R = (mf) * 16 + q15;                                                    \
    int cc = ((ks) * 4 + quad) ^ (((R >> 2) & 1) << 1);                         \
    dst = *(const bf16x8*)&sm[((((buf) << 1) | 0) * 2 + wm) * 8192 + (R * 8 + cc) * 8]; \
  } while (0)

#define RDB8(dst, buf, nf, ks)                                                  \
  do {                                                                          \
    int R = (wn & 1) * 64 + (nf) * 16 + q15;                                    \
    int cc = ((ks) * 4 + quad) ^ (((R >> 2) & 1) << 1);                         \
    dst = *(const bf16x8*)&sm[((((buf) << 1) | 1) * 2 + (wn >> 1)) * 8192 + (R * 8 + cc) * 8]; \
  } while (0)

#define MFMA_Q(mlo, nlo)                                                        \
  do {                                                                          \
    __builtin_amdgcn_s_barrier();                                               \
    asm volatile("s_waitcnt lgkmcnt(0)" ::: "memory");                          \
    __builtin_amdgcn_sched_barrier(0);                                          \
    __builtin_amdgcn_s_setprio(1);                                              \
    _Pragma("unroll")                                                           \
    for (int ks = 0; ks < 2; ++ks)                                              \
      _Pragma("unroll")                                                         \
      for (int mi = 0; mi < 4; ++mi)                                            \
        _Pragma("unroll")                                                       \
        for (int ni = 0; ni < 2; ++ni)                                          \
          acc[(mlo) + mi][(nlo) + ni] = __builtin_amdgcn_mfma_f32_16x16x32_bf16( \
              af[(mlo) + mi][ks], bfr[(nlo) + ni][ks], acc[(mlo) + mi][(nlo) + ni], 0, 0, 0); \
    __builtin_amdgcn_s_setprio(0);                                              \
    __builtin_amdgcn_sched_barrier(0);                                          \
    __builtin_amdgcn_s_barrier();                                               \
  } while (0)

__global__ __launch_bounds__(512, 2) void gemm_out(
    const unsigned short* __restrict__ A,
    const unsigned short* __restrict__ Bw,
    float* __restrict__ outf,
    const float* __restrict__ bias) {
  extern __shared__ unsigned short sm[];   // [buf][op][half][128*64] = 128 KiB
  const int tid = threadIdx.x;
  const int lane = tid & 63;
  const int wv = tid >> 6;
  const int q15 = lane & 15, quad = lane >> 4;
  const int wm = wv >> 2, wn = wv & 3;     // 2 x 4 wave grid; wave tile 128x64
  const int n0 = blockIdx.x * 256, m0 = blockIdx.y * 256;

  f32x4 acc[8][4] = {};
  bf16x8 af[8][2], bfr[4][2];

  // prologue: tile0 (A h0,h1, B h0,h1) -> buf0; tile1 A halves -> buf1
  STAGE8(0, 0, 0, 0); STAGE8(0, 0, 1, 0); STAGE8(0, 1, 0, 0); STAGE8(0, 1, 1, 0);
  STAGE8(1, 0, 0, 1); STAGE8(1, 0, 1, 1);
  asm volatile("s_waitcnt vmcnt(4)" ::: "memory");   // tile0 resident; tile1 A in flight
  __builtin_amdgcn_s_barrier();

  for (int T = 0; T < 32; ++T) {
    const int buf = T & 1;
    // P0: read A0-3, B0-1 (12 x ds_read_b128); stage (T+1) B h0; Q(0,0)
#pragma unroll
    for (int mf = 0; mf < 4; ++mf) { RDA8(af[mf][0], buf, mf, 0); RDA8(af[mf][1], buf, mf, 1); }
#pragma unroll
    for (int nf = 0; nf < 2; ++nf) { RDB8(bfr[nf][0], buf, nf, 0); RDB8(bfr[nf][1], buf, nf, 1); }
    if (T + 1 < 32) STAGE8(buf ^ 1, 1, 0, T + 1);
    MFMA_Q(0, 0);
    // P1: read A4-7, B2-3 (12); stage (T+1) B h1; Q(0,1)
#pragma unroll
    for (int mf = 4; mf < 8; ++mf) { RDA8(af[mf][0], buf, mf, 0); RDA8(af[mf][1], buf, mf, 1); }
#pragma unroll
    for (int nf = 2; nf < 4; ++nf) { RDB8(bfr[nf][0], buf, nf, 0); RDB8(bfr[nf][1], buf, nf, 1); }
    if (T + 1 < 32) STAGE8(buf ^ 1, 1, 1, T + 1);
    MFMA_Q(0, 2);
    // P2: stage (T+2) A h0; Q(1,1)
    if (T + 2 < 32) STAGE8(buf, 0, 0, T + 2);
    MFMA_Q(4, 2);
    // P3: stage (T+2) A h1; counted vmcnt; Q(1,0)
    if (T + 2 < 32) STAGE8(buf, 0, 1, T + 2);
    if (T < 30) { asm volatile("s_waitcnt vmcnt(4)" ::: "memory"); }
    else if (T == 30) { asm volatile("s_waitcnt vmcnt(0)" ::: "memory"); }
    MFMA_Q(4, 0);
  }

  float bv[4];
#pragma unroll
  for (int nf = 0; nf < 4; ++nf) bv[nf] = bias[n0 + wn * 64 + nf * 16 + q15];
#pragma unroll
  for (int mf = 0; mf < 8; ++mf)
#pragma unroll
    for (int nf = 0; nf < 4; ++nf) {
      int col = n0 + wn * 64 + nf * 16 + q15;
      int row = m0 + wm * 128 + mf * 16 + quad * 4;
#pragma unroll
      for (int r = 0; r < 4; ++r)
        outf[(size_t)(row + r) * DIM + col] = acc[mf][nf][r] + bv[nf];
    }
}

// ---------------------------------------------------------------- flash attention
// R8: T14 async-STAGE split — K/V tile staged global->reg (issued before the
// pre-compute barrier) then ds_write after the post-compute barrier; raw
// s_barrier + lgkmcnt(0)-only waits (no __syncthreads: it drains vmcnt(0) and
// would kill the in-flight loads). T5 setprio around MFMA clusters.
__global__ __launch_bounds__(256, 3) void attn_kernel(
    const unsigned short* __restrict__ Q,    // (B*H, S, HD) rope'd * CS
    const unsigned short* __restrict__ Kg,   // (B*H, S, HD) rope'd
    const unsigned short* __restrict__ Vt,   // (B*H, HD, S)
    unsigned short* __restrict__ O) {        // (B, S, H, HD) bf16
  __shared__ unsigned short Ks[64 * 128];
  __shared__ unsigned short Vs[128 * 64];
  __shared__ unsigned short Ps[4 * 32 * 72];
  const int tid = threadIdx.x;
  const int lane = tid & 63, wv = tid >> 6;
  const int q15 = lane & 15, quad = lane >> 4;
  const int bh = blockIdx.x & 63;
  const int t = blockIdx.x >> 6;             // 0..11
  const int nseg = (t < 8) ? 1 : 2;
  const int b = bh >> 4, h = bh & 15;
  unsigned short* Pw = Ps + wv * (32 * 72);

  for (int seg = 0; seg < nseg; ++seg) {
    const int qt = (t < 8) ? (15 - t) : (seg == 0 ? (15 - t) : (t - 8));
    const int q0w = qt * 128 + wv * 32;

    bf16x8 qf[2][4];
#pragma unroll
    for (int nq = 0; nq < 2; ++nq) {
      const unsigned short* qp = Q + ((size_t)bh * SEQ + q0w + nq * 16 + q15) * HD + quad * 8;
#pragma unroll
      for (int ks = 0; ks < 4; ++ks) qf[nq][ks] = *(const bf16x8*)(qp + ks * 32);
    }

    f32x4 oacc[2][8] = {};
    float rs[2] = {0.f, 0.f};
    const int jmax = 2 * qt + 2;
    const int jcap = 2 * qt + (wv >> 1);

    uint4 kreg[4], vreg[4];
    auto issue = [&](int kv) {
#pragma unroll
      for (int i = 0; i < 4; ++i) {
        int l = i * 256 + tid;
        int r = l >> 4, c = (l & 15) ^ (r & 15);
        kreg[i] = *(const uint4*)(Kg + ((size_t)bh * SEQ + kv + r) * HD + c * 8);
      }
#pragma unroll
      for (int i = 0; i < 4; ++i) {
        int l = i * 256 + tid;
        int r = l >> 3, c = (l & 7) ^ (r & 7);
        vreg[i] = *(const uint4*)(Vt + ((size_t)bh * HD + r) * SEQ + kv + c * 8);
      }
    };
    auto commit = [&]() {
#pragma unroll
      for (int i = 0; i < 4; ++i) { int l = i * 256 + tid; *(uint4*)&Ks[l * 8] = kreg[i]; }
#pragma unroll
      for (int i = 0; i < 4; ++i) { int l = i * 256 + tid; *(uint4*)&Vs[l * 8] = vreg[i]; }
    };

    issue(0);
    commit();

    for (int j = 0; j < jmax; ++j) {
      const int kv0 = j * 64;
      if (j + 1 < jmax) issue((j + 1) * 64);       // in flight across compute
      asm volatile("s_waitcnt lgkmcnt(0)" ::: "memory");  // own ds_writes done
      __builtin_amdgcn_s_barrier();                // tile j visible to all
      __builtin_amdgcn_sched_barrier(0);

      if (j <= jcap) {
        const bool edge = (j == jcap);
#pragma unroll
        for (int mi = 0; mi < 4; ++mi) {
          f32x4 st[2] = {};
          __builtin_amdgcn_s_setprio(1);
#pragma unroll
          for (int ks = 0; ks < 4; ++ks) {
            int r = mi * 16 + q15;
            int c = ks * 4 + quad;
            bf16x8 kf = *(const bf16x8*)&Ks[(r * 16 + (c ^ (r & 15))) * 8];
#pragma unroll
            for (int nq = 0; nq < 2; ++nq)
              st[nq] = __builtin_amdgcn_mfma_f32_16x16x32_bf16(kf, qf[nq][ks], st[nq], 0, 0, 0);
          }
          __builtin_amdgcn_s_setprio(0);
#pragma unroll
          for (int nq = 0; nq < 2; ++nq) {
            unsigned int u[4];
#pragma unroll
            for (int r = 0; r < 4; ++r) {
              float p = exp2f(st[nq][r]);
              if (edge) {
                int kv = kv0 + mi * 16 + quad * 4 + r;
                int qq = q0w + nq * 16 + q15;
                p = (kv > qq) ? 0.f : p;
              }
              unsigned int uu = __builtin_bit_cast(unsigned int, p) & 0xffff0000u;
              rs[nq] += __builtin_bit_cast(float, uu);
              u[r] = uu;
            }
            uint2 pk;
            pk.x = (u[0] >> 16) | u[1];
            pk.y = (u[2] >> 16) | u[3];
            *(uint2*)&Pw[(nq * 16 + q15) * 72 + mi * 16 + quad * 4] = pk;
          }
        }
#pragma unroll
        for (int ks = 0; ks < 2; ++ks) {
          bf16x8 pf[2];
#pragma unroll
          for (int mq = 0; mq < 2; ++mq)
            pf[mq] = *(const bf16x8*)&Pw[(mq * 16 + q15) * 72 + ks * 32 + quad * 8];
          __builtin_amdgcn_s_setprio(1);
#pragma unroll
          for (int nf = 0; nf < 8; ++nf) {
            int r = nf * 16 + q15;
            int c = ks * 4 + quad;
            bf16x8 vf = *(const bf16x8*)&Vs[(r * 8 + (c ^ (r & 7))) * 8];
#pragma unroll
            for (int mq = 0; mq < 2; ++mq)
              oacc[mq][nf] = __builtin_amdgcn_mfma_f32_16x16x32_bf16(pf[mq], vf, oacc[mq][nf], 0, 0, 0);
          }
          __builtin_amdgcn_s_setprio(0);
        }
      }

      asm volatile("s_waitcnt lgkmcnt(0)" ::: "memory");  // all reads of tile j done
      __builtin_amdgcn_s_barrier();
      __builtin_amdgcn_sched_barrier(0);
      if (j + 1 < jmax) commit();                  // vmcnt wait inserted here by compiler
    }

    // segment epilogue: reduce row sums across quads, write O
#pragma unroll
    for (int nq = 0; nq < 2; ++nq) {
      rs[nq] += __shfl_xor(rs[nq], 16);
      rs[nq] += __shfl_xor(rs[nq], 32);
    }
#pragma unroll
    for (int mq = 0; mq < 2; ++mq) {
#pragma unroll
      for (int r = 0; r < 4; ++r) {
        float l = __shfl(rs[mq], quad * 4 + r);
        float inv = 1.0f / l;
        int qq = q0w + mq * 16 + quad * 4 + r;
        size_t base = (((size_t)b * SEQ + qq) * NH + h) * HD;
#pragma unroll
        for (int nf = 0; nf < 8; ++nf)
          O[base + nf * 16 + q15] = f2bf(oacc[mq][nf][r] * inv);
      }
    }
  }
}

// ---------------------------------------------------------------- launch
extern "C" void kernel_launch(void* const* d_in, const int* in_sizes, int n_in,
                              void* d_out, int out_size, void* d_ws, size_t ws_size,
                              hipStream_t stream) {
  (void)in_sizes; (void)n_in; (void)out_size; (void)ws_size;
  const float* x  = (const float*)d_in[0];
  const float* Wq = (const float*)d_in[1];
  const float* Wk = (const float*)d_in[2];
  const float* Wv = (const float*)d_in[3];
  const float* Wo = (const float*)d_in[4];
  const float* bo = (const float*)d_in[5];
  float* out = (float*)d_out;

  const size_t XE = (size_t)BATCH * SEQ * DIM;   // 16.7M elems
  const size_t WE = (size_t)DIM * DIM;           // 4.2M elems

  char* p = (char*)d_ws;
  unsigned short* xb   = (unsigned short*)p; p += XE * 2;
  unsigned short* Wall = (unsigned short*)p; p += 4 * WE * 2;
  unsigned short* Qg   = (unsigned short*)p; p += XE * 2;
  unsigned short* Kb   = (unsigned short*)p; p += XE * 2;
  unsigned short* Vtb  = (unsigned short*)p; p += XE * 2;
  unsigned short* attn = (unsigned short*)p; p += XE * 2;

  static bool attr_set = false;
  if (!attr_set) {
    hipFuncSetAttribute((const void*)gemm_out,
                        hipFuncAttributeMaxDynamicSharedMemorySize, 131072);
    attr_set = true;
  }

  cast_all_kernel<<<(int)(2 * XE / 4 / 256), 256, 0, stream>>>(x, Wq, Wk, Wv, Wo, xb);

  gemm_qkv<<<dim3(48, 64), 256, 0, stream>>>(
      xb, Wall, Wall + WE, Wall + 2 * WE, Qg, Kb, Vtb);

  attn_kernel<<<dim3(768), 256, 0, stream>>>(Qg, Kb, Vtb, attn);

  gemm_out<<<dim3(DIM / 256, (BATCH * SEQ) / 256), 512, 131072, stream>>>(
      attn, Wall + 3 * WE, out, bo);
}

// Round 3
// 692.427 us; speedup vs baseline: 1.2474x; 1.2474x over previous
//
#include <hip/hip_runtime.h>

#define BATCH 4
#define SEQ   2048
#define DIM   2048
#define NH    16
#define HD    128

typedef __bf16 bf16x8 __attribute__((ext_vector_type(8)));
typedef float  f32x4  __attribute__((ext_vector_type(4)));

__device__ __forceinline__ unsigned short f2bf(float f) {
  unsigned int u = __builtin_bit_cast(unsigned int, f);
  u += 0x7fffu + ((u >> 16) & 1u);          // RNE
  return (unsigned short)(u >> 16);
}

// async global->LDS, 16B per lane; LDS dest must be wave-uniform-base + lane*16
__device__ __forceinline__ void async16(void* lds, const void* g) {
  __builtin_amdgcn_global_load_lds(
      (const __attribute__((address_space(1))) unsigned int*)g,
      (__attribute__((address_space(3))) unsigned int*)lds, 16, 0, 0);
}

// ---------------------------------------------------------------- one cast dispatch for x + all 4 weights
__global__ __launch_bounds__(256) void cast_all_kernel(
    const float* __restrict__ x,
    const float* __restrict__ w0, const float* __restrict__ w1,
    const float* __restrict__ w2, const float* __restrict__ w3,
    unsigned short* __restrict__ dst) {
  int i = blockIdx.x * 256 + threadIdx.x;
  const float* s;
  int loc;
  if (i < (1 << 22)) { s = x; loc = i; }
  else {
    int k = i - (1 << 22);
    int sel = k >> 20; loc = k & 0xfffff;
    s = sel == 0 ? w0 : sel == 1 ? w1 : sel == 2 ? w2 : w3;
  }
  float4 v = ((const float4*)s)[loc];
  ushort4 o;
  o.x = f2bf(v.x); o.y = f2bf(v.y); o.z = f2bf(v.z); o.w = f2bf(v.w);
  ((ushort4*)dst)[i] = o;
}

// ---------------------------------------------------------------- fused QKV GEMM + RoPE + V-transpose
// (unchanged; 8-phase port waits for a validated gemm_out core)
__global__ __launch_bounds__(256) void gemm_qkv(
    const unsigned short* __restrict__ A,    // xb (8192 x 2048) bf16
    const unsigned short* __restrict__ Wq,
    const unsigned short* __restrict__ Wk,
    const unsigned short* __restrict__ Wv,
    unsigned short* __restrict__ Qo,
    unsigned short* __restrict__ Ko,
    unsigned short* __restrict__ Vto) {
  __shared__ unsigned short As[128 * 32];
  __shared__ unsigned short Bs[128 * 32];
  __shared__ float ep[32 * 132];
  const int tid = threadIdx.x;
  const int lane = tid & 63, wv = tid >> 6;
  const int q15 = lane & 15, quad = lane >> 4;
  const int wm = wv >> 1, wn = wv & 1;
  const int gx = blockIdx.x;
  const int sel = gx >> 4, h = gx & 15;
  const int m0 = blockIdx.y * 128;
  const unsigned short* Bw =
      (sel == 0 ? Wq : (sel == 1 ? Wk : Wv)) + (size_t)h * 128 * DIM;

  f32x4 acc[4][4] = {};

  for (int kt = 0; kt < DIM; kt += 32) {
    __syncthreads();
#pragma unroll
    for (int i = 0; i < 2; ++i) {
      int l = i * 256 + tid;
      int r = l >> 2, s = l & 3;
      int c = (s - (r >> 1)) & 3;
      async16(&As[l * 8], A + (size_t)(m0 + r) * DIM + kt + c * 8);
    }
#pragma unroll
    for (int i = 0; i < 2; ++i) {
      int l = i * 256 + tid;
      int r = l >> 2, s = l & 3;
      int c = (s - (r >> 1)) & 3;
      async16(&Bs[l * 8], Bw + (size_t)r * DIM + kt + c * 8);
    }
    __syncthreads();

    bf16x8 af[4], bf[4];
#pragma unroll
    for (int mf = 0; mf < 4; ++mf) {
      int r = wm * 64 + mf * 16 + q15;
      int sl = r * 4 + ((quad + (r >> 1)) & 3);
      af[mf] = *(const bf16x8*)&As[sl * 8];
    }
#pragma unroll
    for (int nf = 0; nf < 4; ++nf) {
      int r = wn * 64 + nf * 16 + q15;
      int sl = r * 4 + ((quad + (r >> 1)) & 3);
      bf[nf] = *(const bf16x8*)&Bs[sl * 8];
    }
#pragma unroll
    for (int mf = 0; mf < 4; ++mf)
#pragma unroll
      for (int nf = 0; nf < 4; ++nf)
        acc[mf][nf] = __builtin_amdgcn_mfma_f32_16x16x32_bf16(af[mf], bf[nf], acc[mf][nf], 0, 0, 0);
  }

  const int b = m0 >> 11;
  const int s0 = m0 & (SEQ - 1);
  const int bh = b * NH + h;
  const float CS = 0.12751744f;

  float invf[2][8];
  if (sel < 2) {
#pragma unroll
    for (int oi = 0; oi < 2; ++oi) {
      int oc = ((oi * 256 + tid) & 15) * 8;
#pragma unroll
      for (int j = 0; j < 8; ++j)
        invf[oi][j] = exp2f(-(float)((oc & 63) + j) * 0.20762050593046932f);
    }
  }

  for (int c = 0; c < 4; ++c) {
    __syncthreads();
    if (wm == (c >> 1)) {
      int mfb = (c & 1) * 2;
#pragma unroll
      for (int mi = 0; mi < 2; ++mi) {
        int mf = mfb + mi;
        int rr0 = mf * 16 + quad * 4 - (c & 1) * 32;
#pragma unroll
        for (int nf = 0; nf < 4; ++nf) {
          int col = wn * 64 + nf * 16 + q15;
#pragma unroll
          for (int r = 0; r < 4; ++r)
            ep[(rr0 + r) * 132 + col] = acc[mf][nf][r];
        }
      }
    }
    __syncthreads();
#pragma unroll
    for (int oi = 0; oi < 2; ++oi) {
      int o = oi * 256 + tid;
      if (sel < 2) {
        int rr = o >> 4, oc = (o & 15) * 8;
        int s = s0 + c * 32 + rr;
        float sf = (float)s;
        float4 a0 = *(const float4*)&ep[rr * 132 + oc];
        float4 a1 = *(const float4*)&ep[rr * 132 + oc + 4];
        float4 b0 = *(const float4*)&ep[rr * 132 + (oc ^ 64)];
        float4 b1 = *(const float4*)&ep[rr * 132 + (oc ^ 64) + 4];
        float av[8] = {a0.x, a0.y, a0.z, a0.w, a1.x, a1.y, a1.z, a1.w};
        float bv[8] = {b0.x, b0.y, b0.z, b0.w, b1.x, b1.y, b1.z, b1.w};
        float sgn = (oc & 64) ? 1.f : -1.f;
        float scl = (sel == 0) ? CS : 1.0f;
        unsigned short u[8];
#pragma unroll
        for (int j = 0; j < 8; ++j) {
          float ang = sf * invf[oi][j];
          float cc = __cosf(ang), ss = __sinf(ang);
          u[j] = f2bf((av[j] * cc + sgn * bv[j] * ss) * scl);
        }
        unsigned short* dst = (sel == 0 ? Qo : Ko) + ((size_t)bh * SEQ + s) * HD + oc;
        *(uint4*)dst = *(uint4*)u;
      } else {
        int hd = o & 127, so8 = (o >> 7) * 8;
        unsigned short u[8];
#pragma unroll
        for (int k = 0; k < 8; ++k)
          u[k] = f2bf(ep[(so8 + k) * 132 + hd]);
        *(uint4*)(Vto + ((size_t)bh * HD + hd) * SEQ + (s0 + c * 32 + so8)) = *(uint4*)u;
      }
    }
  }
}

// ---------------------------------------------------------------- O-projection GEMM, 256x256 deep-pipelined
// R3: identical schedule to R2 (harness-validated correct) EXCEPT all
// sched_barrier(0) calls removed — m141 precedent: sched_barrier(0) pinning
// regressed the same structure 874->510 TF by defeating the compiler's own
// fine-grained lgkmcnt scheduling. Barriers / per-phase lgkmcnt(0) / counted
// vmcnt(4) / setprio / st_16x32 swizzle unchanged.
#define STAGE8(buf, op, half, kt)                                               \
  do {                                                                          \
    const unsigned short* Gp = (op) ? Bw : A;                                   \
    const int rb = ((op) ? n0 : m0) + (half) * 128;                             \
    unsigned short* hb = sm + ((((buf) << 1) | (op)) * 2 + (half)) * 8192;      \
    _Pragma("unroll")                                                           \
    for (int jj = 0; jj < 2; ++jj) {                                            \
      int l = jj * 512 + tid;                                                   \
      int rr = l >> 3, cc = l & 7;                                              \
      int cs = cc ^ (((rr >> 2) & 1) << 1);                                     \
      async16(&hb[l * 8], Gp + (size_t)(rb + rr) * DIM + (kt) * 64 + cs * 8);   \
    }                                                                           \
  } while (0)

#define RDA8(dst, buf, mf, ks)                                                  \
  do {                                                                          \
    int R = (mf) * 16 + q15;                                                    \
    int cc = ((ks) * 4 + quad) ^ (((R >> 2) & 1) << 1);                         \
    dst = *(const bf16x8*)&sm[((((buf) << 1) | 0) * 2 + wm) * 8192 + (R * 8 + cc) * 8]; \
  } while (0)

#define RDB8(dst, buf, nf, ks)                                                  \
  do {                                                                          \
    int R = (wn & 1) * 64 + (nf) * 16 + q15;                                    \
    int cc = ((ks) * 4 + quad) ^ (((R >> 2) & 1) << 1);                         \
    dst = *(const bf16x8*)&sm[((((buf) << 1) | 1) * 2 + (wn >> 1)) * 8192 + (R * 8 + cc) * 8]; \
  } while (0)

#define MFMA_Q(mlo, nlo)                                                        \
  do {                                                                          \
    __builtin_amdgcn_s_barrier();                                               \
    asm volatile("s_waitcnt lgkmcnt(0)" ::: "memory");                          \
    __builtin_amdgcn_s_setprio(1);                                              \
    _Pragma("unroll")                                                           \
    for (int ks = 0; ks < 2; ++ks)                                              \
      _Pragma("unroll")                                                         \
      for (int mi = 0; mi < 4; ++mi)                                            \
        _Pragma("unroll")                                                       \
        for (int ni = 0; ni < 2; ++ni)                                          \
          acc[(mlo) + mi][(nlo) + ni] = __builtin_amdgcn_mfma_f32_16x16x32_bf16( \
              af[(mlo) + mi][ks], bfr[(nlo) + ni][ks], acc[(mlo) + mi][(nlo) + ni], 0, 0, 0); \
    __builtin_amdgcn_s_setprio(0);                                              \
    __builtin_amdgcn_s_barrier();                                               \
  } while (0)

__global__ __launch_bounds__(512, 2) void gemm_out(
    const unsigned short* __restrict__ A,
    const unsigned short* __restrict__ Bw,
    float* __restrict__ outf,
    const float* __restrict__ bias) {
  extern __shared__ unsigned short sm[];   // [buf][op][half][128*64] = 128 KiB
  const int tid = threadIdx.x;
  const int lane = tid & 63;
  const int wv = tid >> 6;
  const int q15 = lane & 15, quad = lane >> 4;
  const int wm = wv >> 2, wn = wv & 3;     // 2 x 4 wave grid; wave tile 128x64
  const int n0 = blockIdx.x * 256, m0 = blockIdx.y * 256;

  f32x4 acc[8][4] = {};
  bf16x8 af[8][2], bfr[4][2];

  // prologue: tile0 (A h0,h1, B h0,h1) -> buf0; tile1 A halves -> buf1
  STAGE8(0, 0, 0, 0); STAGE8(0, 0, 1, 0); STAGE8(0, 1, 0, 0); STAGE8(0, 1, 1, 0);
  STAGE8(1, 0, 0, 1); STAGE8(1, 0, 1, 1);
  asm volatile("s_waitcnt vmcnt(4)" ::: "memory");   // tile0 resident; tile1 A in flight
  __builtin_amdgcn_s_barrier();

  for (int T = 0; T < 32; ++T) {
    const int buf = T & 1;
    // P0: read A0-3, B0-1 (12 x ds_read_b128); stage (T+1) B h0; Q(0,0)
#pragma unroll
    for (int mf = 0; mf < 4; ++mf) { RDA8(af[mf][0], buf, mf, 0); RDA8(af[mf][1], buf, mf, 1); }
#pragma unroll
    for (int nf = 0; nf < 2; ++nf) { RDB8(bfr[nf][0], buf, nf, 0); RDB8(bfr[nf][1], buf, nf, 1); }
    if (T + 1 < 32) STAGE8(buf ^ 1, 1, 0, T + 1);
    MFMA_Q(0, 0);
    // P1: read A4-7, B2-3 (12); stage (T+1) B h1; Q(0,1)
#pragma unroll
    for (int mf = 4; mf < 8; ++mf) { RDA8(af[mf][0], buf, mf, 0); RDA8(af[mf][1], buf, mf, 1); }
#pragma unroll
    for (int nf = 2; nf < 4; ++nf) { RDB8(bfr[nf][0], buf, nf, 0); RDB8(bfr[nf][1], buf, nf, 1); }
    if (T + 1 < 32) STAGE8(buf ^ 1, 1, 1, T + 1);
    MFMA_Q(0, 2);
    // P2: stage (T+2) A h0; Q(1,1)
    if (T + 2 < 32) STAGE8(buf, 0, 0, T + 2);
    MFMA_Q(4, 2);
    // P3: stage (T+2) A h1; counted vmcnt; Q(1,0)
    if (T + 2 < 32) STAGE8(buf, 0, 1, T + 2);
    if (T < 30) { asm volatile("s_waitcnt vmcnt(4)" ::: "memory"); }
    else if (T == 30) { asm volatile("s_waitcnt vmcnt(0)" ::: "memory"); }
    MFMA_Q(4, 0);
  }

  float bv[4];
#pragma unroll
  for (int nf = 0; nf < 4; ++nf) bv[nf] = bias[n0 + wn * 64 + nf * 16 + q15];
#pragma unroll
  for (int mf = 0; mf < 8; ++mf)
#pragma unroll
    for (int nf = 0; nf < 4; ++nf) {
      int col = n0 + wn * 64 + nf * 16 + q15;
      int row = m0 + wm * 128 + mf * 16 + quad * 4;
#pragma unroll
      for (int r = 0; r < 4; ++r)
        outf[(size_t)(row + r) * DIM + col] = acc[mf][nf][r] + bv[nf];
    }
}

// ---------------------------------------------------------------- flash attention (R0 structure, reverted — known-good)
// Per bh: t in 0..11. t<8: single q-tile qt=15-t; t>=8: paired {15-t, t-8} = 18 iters.
// 768 blocks = 3 blocks/CU co-resident. 4 waves x 32 q rows, KV tiles of 64,
// St-swap (softmax rows in-register), fixed-max softmax, Q pre-scaled.
// R2 lesson: VGPR-staged async split + launch_bounds(256,3) forced VGPR cap 84
// -> spills (566MB writes, MfmaUtil 0.6%). Reverted verbatim.
__global__ __launch_bounds__(256) void attn_kernel(
    const unsigned short* __restrict__ Q,    // (B*H, S, HD) rope'd * CS
    const unsigned short* __restrict__ Kg,   // (B*H, S, HD) rope'd
    const unsigned short* __restrict__ Vt,   // (B*H, HD, S)
    unsigned short* __restrict__ O) {        // (B, S, H, HD) bf16
  __shared__ unsigned short Ks[64 * 128];
  __shared__ unsigned short Vs[128 * 64];
  __shared__ unsigned short Ps[4 * 32 * 72];
  const int tid = threadIdx.x;
  const int lane = tid & 63, wv = tid >> 6;
  const int q15 = lane & 15, quad = lane >> 4;
  const int bh = blockIdx.x & 63;
  const int t = blockIdx.x >> 6;             // 0..11
  const int nseg = (t < 8) ? 1 : 2;
  const int b = bh >> 4, h = bh & 15;
  unsigned short* Pw = Ps + wv * (32 * 72);

  for (int seg = 0; seg < nseg; ++seg) {
    const int qt = (t < 8) ? (15 - t) : (seg == 0 ? (15 - t) : (t - 8));
    const int q0w = qt * 128 + wv * 32;

    bf16x8 qf[2][4];
#pragma unroll
    for (int nq = 0; nq < 2; ++nq) {
      const unsigned short* qp = Q + ((size_t)bh * SEQ + q0w + nq * 16 + q15) * HD + quad * 8;
#pragma unroll
      for (int ks = 0; ks < 4; ++ks) qf[nq][ks] = *(const bf16x8*)(qp + ks * 32);
    }

    f32x4 oacc[2][8] = {};
    float rs[2] = {0.f, 0.f};
    const int jmax = 2 * qt + 2;
    const int jcap = 2 * qt + (wv >> 1);

    for (int j = 0; j < jmax; ++j) {
      const int kv0 = j * 64;
      __syncthreads();
#pragma unroll
      for (int i = 0; i < 4; ++i) {
        int l = i * 256 + tid;
        int r = l >> 4, c = (l & 15) ^ (r & 15);
        async16(&Ks[l * 8], Kg + ((size_t)bh * SEQ + kv0 + r) * HD + c * 8);
      }
#pragma unroll
      for (int i = 0; i < 4; ++i) {
        int l = i * 256 + tid;
        int r = l >> 3, c = (l & 7) ^ (r & 7);
        async16(&Vs[l * 8], Vt + ((size_t)bh * HD + r) * SEQ + kv0 + c * 8);
      }
      __syncthreads();

      if (j <= jcap) {
        const bool edge = (j == jcap);
#pragma unroll
        for (int mi = 0; mi < 4; ++mi) {
          f32x4 st[2] = {};
#pragma unroll
          for (int ks = 0; ks < 4; ++ks) {
            int r = mi * 16 + q15;
            int c = ks * 4 + quad;
            bf16x8 kf = *(const bf16x8*)&Ks[(r * 16 + (c ^ (r & 15))) * 8];
#pragma unroll
            for (int nq = 0; nq < 2; ++nq)
              st[nq] = __builtin_amdgcn_mfma_f32_16x16x32_bf16(kf, qf[nq][ks], st[nq], 0, 0, 0);
          }
#pragma unroll
          for (int nq = 0; nq < 2; ++nq) {
            unsigned int u[4];
#pragma unroll
            for (int r = 0; r < 4; ++r) {
              float p = exp2f(st[nq][r]);
              if (edge) {
                int kv = kv0 + mi * 16 + quad * 4 + r;
                int qq = q0w + nq * 16 + q15;
                p = (kv > qq) ? 0.f : p;
              }
              unsigned int uu = __builtin_bit_cast(unsigned int, p) & 0xffff0000u;
              rs[nq] += __builtin_bit_cast(float, uu);
              u[r] = uu;
            }
            uint2 pk;
            pk.x = (u[0] >> 16) | u[1];
            pk.y = (u[2] >> 16) | u[3];
            *(uint2*)&Pw[(nq * 16 + q15) * 72 + mi * 16 + quad * 4] = pk;
          }
        }
#pragma unroll
        for (int ks = 0; ks < 2; ++ks) {
          bf16x8 pf[2];
#pragma unroll
          for (int mq = 0; mq < 2; ++mq)
            pf[mq] = *(const bf16x8*)&Pw[(mq * 16 + q15) * 72 + ks * 32 + quad * 8];
#pragma unroll
          for (int nf = 0; nf < 8; ++nf) {
            int r = nf * 16 + q15;
            int c = ks * 4 + quad;
            bf16x8 vf = *(const bf16x8*)&Vs[(r * 8 + (c ^ (r & 7))) * 8];
#pragma unroll
            for (int mq = 0; mq < 2; ++mq)
              oacc[mq][nf] = __builtin_amdgcn_mfma_f32_16x16x32_bf16(pf[mq], vf, oacc[mq][nf], 0, 0, 0);
          }
        }
      }
    }

    // segment epilogue: reduce row sums across quads, write O
#pragma unroll
    for (int nq = 0; nq < 2; ++nq) {
      rs[nq] += __shfl_xor(rs[nq], 16);
      rs[nq] += __shfl_xor(rs[nq], 32);
    }
#pragma unroll
    for (int mq = 0; mq < 2; ++mq) {
#pragma unroll
      for (int r = 0; r < 4; ++r) {
        float l = __shfl(rs[mq], quad * 4 + r);
        float inv = 1.0f / l;
        int qq = q0w + mq * 16 + quad * 4 + r;
        size_t base = (((size_t)b * SEQ + qq) * NH + h) * HD;
#pragma unroll
        for (int nf = 0; nf < 8; ++nf)
          O[base + nf * 16 + q15] = f2bf(oacc[mq][nf][r] * inv);
      }
    }
  }
}

// ---------------------------------------------------------------- launch
extern "C" void kernel_launch(void* const* d_in, const int* in_sizes, int n_in,
                              void* d_out, int out_size, void* d_ws, size_t ws_size,
                              hipStream_t stream) {
  (void)in_sizes; (void)n_in; (void)out_size; (void)ws_size;
  const float* x  = (const float*)d_in[0];
  const float* Wq = (const float*)d_in[1];
  const float* Wk = (const float*)d_in[2];
  const float* Wv = (const float*)d_in[3];
  const float* Wo = (const float*)d_in[4];
  const float* bo = (const float*)d_in[5];
  float* out = (float*)d_out;

  const size_t XE = (size_t)BATCH * SEQ * DIM;   // 16.7M elems
  const size_t WE = (size_t)DIM * DIM;           // 4.2M elems

  char* p = (char*)d_ws;
  unsigned short* xb   = (unsigned short*)p; p += XE * 2;
  unsigned short* Wall = (unsigned short*)p; p += 4 * WE * 2;
  unsigned short* Qg   = (unsigned short*)p; p += XE * 2;
  unsigned short* Kb   = (unsigned short*)p; p += XE * 2;
  unsigned short* Vtb  = (unsigned short*)p; p += XE * 2;
  unsigned short* attn = (unsigned short*)p; p += XE * 2;

  static bool attr_set = false;
  if (!attr_set) {
    hipFuncSetAttribute((const void*)gemm_out,
                        hipFuncAttributeMaxDynamicSharedMemorySize, 131072);
    attr_set = true;
  }

  cast_all_kernel<<<(int)(2 * XE / 4 / 256), 256, 0, stream>>>(x, Wq, Wk, Wv, Wo, xb);

  gemm_qkv<<<dim3(48, 64), 256, 0, stream>>>(
      xb, Wall, Wall + WE, Wall + 2 * WE, Qg, Kb, Vtb);

  attn_kernel<<<dim3(768), 256, 0, stream>>>(Qg, Kb, Vtb, attn);

  gemm_out<<<dim3(DIM / 256, (BATCH * SEQ) / 256), 512, 131072, stream>>>(
      attn, Wall + 3 * WE, out, bo);
}

// Round 4
// 681.915 us; speedup vs baseline: 1.2667x; 1.0154x over previous
//
#include <hip/hip_runtime.h>

#define BATCH 4
#define SEQ   2048
#define DIM   2048
#define NH    16
#define HD    128

typedef __bf16 bf16x8 __attribute__((ext_vector_type(8)));
typedef float  f32x4  __attribute__((ext_vector_type(4)));

__device__ __forceinline__ unsigned short f2bf(float f) {
  unsigned int u = __builtin_bit_cast(unsigned int, f);
  u += 0x7fffu + ((u >> 16) & 1u);          // RNE
  return (unsigned short)(u >> 16);
}

// async global->LDS, 16B per lane; LDS dest must be wave-uniform-base + lane*16
__device__ __forceinline__ void async16(void* lds, const void* g) {
  __builtin_amdgcn_global_load_lds(
      (const __attribute__((address_space(1))) unsigned int*)g,
      (__attribute__((address_space(3))) unsigned int*)lds, 16, 0, 0);
}

// ---------------------------------------------------------------- one cast dispatch for x + all 4 weights
__global__ __launch_bounds__(256) void cast_all_kernel(
    const float* __restrict__ x,
    const float* __restrict__ w0, const float* __restrict__ w1,
    const float* __restrict__ w2, const float* __restrict__ w3,
    unsigned short* __restrict__ dst) {
  int i = blockIdx.x * 256 + threadIdx.x;
  const float* s;
  int loc;
  if (i < (1 << 22)) { s = x; loc = i; }
  else {
    int k = i - (1 << 22);
    int sel = k >> 20; loc = k & 0xfffff;
    s = sel == 0 ? w0 : sel == 1 ? w1 : sel == 2 ? w2 : w3;
  }
  float4 v = ((const float4*)s)[loc];
  ushort4 o;
  o.x = f2bf(v.x); o.y = f2bf(v.y); o.z = f2bf(v.z); o.w = f2bf(v.w);
  ((ushort4*)dst)[i] = o;
}

// ---------------------------------------------------------------- fused QKV GEMM + RoPE + V-transpose
// (unchanged; 8-phase port waits for a validated gemm_out core)
__global__ __launch_bounds__(256) void gemm_qkv(
    const unsigned short* __restrict__ A,    // xb (8192 x 2048) bf16
    const unsigned short* __restrict__ Wq,
    const unsigned short* __restrict__ Wk,
    const unsigned short* __restrict__ Wv,
    unsigned short* __restrict__ Qo,
    unsigned short* __restrict__ Ko,
    unsigned short* __restrict__ Vto) {
  __shared__ unsigned short As[128 * 32];
  __shared__ unsigned short Bs[128 * 32];
  __shared__ float ep[32 * 132];
  const int tid = threadIdx.x;
  const int lane = tid & 63, wv = tid >> 6;
  const int q15 = lane & 15, quad = lane >> 4;
  const int wm = wv >> 1, wn = wv & 1;
  const int gx = blockIdx.x;
  const int sel = gx >> 4, h = gx & 15;
  const int m0 = blockIdx.y * 128;
  const unsigned short* Bw =
      (sel == 0 ? Wq : (sel == 1 ? Wk : Wv)) + (size_t)h * 128 * DIM;

  f32x4 acc[4][4] = {};

  for (int kt = 0; kt < DIM; kt += 32) {
    __syncthreads();
#pragma unroll
    for (int i = 0; i < 2; ++i) {
      int l = i * 256 + tid;
      int r = l >> 2, s = l & 3;
      int c = (s - (r >> 1)) & 3;
      async16(&As[l * 8], A + (size_t)(m0 + r) * DIM + kt + c * 8);
    }
#pragma unroll
    for (int i = 0; i < 2; ++i) {
      int l = i * 256 + tid;
      int r = l >> 2, s = l & 3;
      int c = (s - (r >> 1)) & 3;
      async16(&Bs[l * 8], Bw + (size_t)r * DIM + kt + c * 8);
    }
    __syncthreads();

    bf16x8 af[4], bf[4];
#pragma unroll
    for (int mf = 0; mf < 4; ++mf) {
      int r = wm * 64 + mf * 16 + q15;
      int sl = r * 4 + ((quad + (r >> 1)) & 3);
      af[mf] = *(const bf16x8*)&As[sl * 8];
    }
#pragma unroll
    for (int nf = 0; nf < 4; ++nf) {
      int r = wn * 64 + nf * 16 + q15;
      int sl = r * 4 + ((quad + (r >> 1)) & 3);
      bf[nf] = *(const bf16x8*)&Bs[sl * 8];
    }
#pragma unroll
    for (int mf = 0; mf < 4; ++mf)
#pragma unroll
      for (int nf = 0; nf < 4; ++nf)
        acc[mf][nf] = __builtin_amdgcn_mfma_f32_16x16x32_bf16(af[mf], bf[nf], acc[mf][nf], 0, 0, 0);
  }

  const int b = m0 >> 11;
  const int s0 = m0 & (SEQ - 1);
  const int bh = b * NH + h;
  const float CS = 0.12751744f;

  float invf[2][8];
  if (sel < 2) {
#pragma unroll
    for (int oi = 0; oi < 2; ++oi) {
      int oc = ((oi * 256 + tid) & 15) * 8;
#pragma unroll
      for (int j = 0; j < 8; ++j)
        invf[oi][j] = exp2f(-(float)((oc & 63) + j) * 0.20762050593046932f);
    }
  }

  for (int c = 0; c < 4; ++c) {
    __syncthreads();
    if (wm == (c >> 1)) {
      int mfb = (c & 1) * 2;
#pragma unroll
      for (int mi = 0; mi < 2; ++mi) {
        int mf = mfb + mi;
        int rr0 = mf * 16 + quad * 4 - (c & 1) * 32;
#pragma unroll
        for (int nf = 0; nf < 4; ++nf) {
          int col = wn * 64 + nf * 16 + q15;
#pragma unroll
          for (int r = 0; r < 4; ++r)
            ep[(rr0 + r) * 132 + col] = acc[mf][nf][r];
        }
      }
    }
    __syncthreads();
#pragma unroll
    for (int oi = 0; oi < 2; ++oi) {
      int o = oi * 256 + tid;
      if (sel < 2) {
        int rr = o >> 4, oc = (o & 15) * 8;
        int s = s0 + c * 32 + rr;
        float sf = (float)s;
        float4 a0 = *(const float4*)&ep[rr * 132 + oc];
        float4 a1 = *(const float4*)&ep[rr * 132 + oc + 4];
        float4 b0 = *(const float4*)&ep[rr * 132 + (oc ^ 64)];
        float4 b1 = *(const float4*)&ep[rr * 132 + (oc ^ 64) + 4];
        float av[8] = {a0.x, a0.y, a0.z, a0.w, a1.x, a1.y, a1.z, a1.w};
        float bv[8] = {b0.x, b0.y, b0.z, b0.w, b1.x, b1.y, b1.z, b1.w};
        float sgn = (oc & 64) ? 1.f : -1.f;
        float scl = (sel == 0) ? CS : 1.0f;
        unsigned short u[8];
#pragma unroll
        for (int j = 0; j < 8; ++j) {
          float ang = sf * invf[oi][j];
          float cc = __cosf(ang), ss = __sinf(ang);
          u[j] = f2bf((av[j] * cc + sgn * bv[j] * ss) * scl);
        }
        unsigned short* dst = (sel == 0 ? Qo : Ko) + ((size_t)bh * SEQ + s) * HD + oc;
        *(uint4*)dst = *(uint4*)u;
      } else {
        int hd = o & 127, so8 = (o >> 7) * 8;
        unsigned short u[8];
#pragma unroll
        for (int k = 0; k < 8; ++k)
          u[k] = f2bf(ep[(so8 + k) * 132 + hd]);
        *(uint4*)(Vto + ((size_t)bh * HD + hd) * SEQ + (s0 + c * 32 + so8)) = *(uint4*)u;
      }
    }
  }
}

// ---------------------------------------------------------------- O-projection GEMM, 256x256 deep-pipelined
// R4: swizzle upgraded 1-bit -> 3-bit (G4 recipe: byte ^= (row&7)<<4, i.e.
// chunk ^= row&7). R3's 1-bit XOR left an 8-way read conflict (every 128B row
// starts at bank 0; chunk spread over only 2 values). 3-bit spreads 16 rows
// of a quad-group over all 8 chunks -> 2 lanes/chunk = conflict-free (m136).
// Same involution on stage source and read address; schedule unchanged
// (harness-validated in R2/R3).
#define STAGE8(buf, op, half, kt)                                               \
  do {                                                                          \
    const unsigned short* Gp = (op) ? Bw : A;                                   \
    const int rb = ((op) ? n0 : m0) + (half) * 128;                             \
    unsigned short* hb = sm + ((((buf) << 1) | (op)) * 2 + (half)) * 8192;      \
    _Pragma("unroll")                                                           \
    for (int jj = 0; jj < 2; ++jj) {                                            \
      int l = jj * 512 + tid;                                                   \
      int rr = l >> 3, cc = l & 7;                                              \
      int cs = cc ^ (rr & 7);                                                   \
      async16(&hb[l * 8], Gp + (size_t)(rb + rr) * DIM + (kt) * 64 + cs * 8);   \
    }                                                                           \
  } while (0)

#define RDA8(dst, buf, mf, ks)                                                  \
  do {                                                                          \
    int R = (mf) * 16 + q15;                                                    \
    int cc = ((ks) * 4 + quad) ^ (R & 7);                                       \
    dst = *(const bf16x8*)&sm[((((buf) << 1) | 0) * 2 + wm) * 8192 + (R * 8 + cc) * 8]; \
  } while (0)

#define RDB8(dst, buf, nf, ks)                                                  \
  do {                                                                          \
    int R = (wn & 1) * 64 + (nf) * 16 + q15;                                    \
    int cc = ((ks) * 4 + quad) ^ (R & 7);                                       \
    dst = *(const bf16x8*)&sm[((((buf) << 1) | 1) * 2 + (wn >> 1)) * 8192 + (R * 8 + cc) * 8]; \
  } while (0)

#define MFMA_Q(mlo, nlo)                                                        \
  do {                                                                          \
    __builtin_amdgcn_s_barrier();                                               \
    asm volatile("s_waitcnt lgkmcnt(0)" ::: "memory");                          \
    __builtin_amdgcn_s_setprio(1);                                              \
    _Pragma("unroll")                                                           \
    for (int ks = 0; ks < 2; ++ks)                                              \
      _Pragma("unroll")                                                         \
      for (int mi = 0; mi < 4; ++mi)                                            \
        _Pragma("unroll")                                                       \
        for (int ni = 0; ni < 2; ++ni)                                          \
          acc[(mlo) + mi][(nlo) + ni] = __builtin_amdgcn_mfma_f32_16x16x32_bf16( \
              af[(mlo) + mi][ks], bfr[(nlo) + ni][ks], acc[(mlo) + mi][(nlo) + ni], 0, 0, 0); \
    __builtin_amdgcn_s_setprio(0);                                              \
    __builtin_amdgcn_s_barrier();                                               \
  } while (0)

__global__ __launch_bounds__(512, 2) void gemm_out(
    const unsigned short* __restrict__ A,
    const unsigned short* __restrict__ Bw,
    float* __restrict__ outf,
    const float* __restrict__ bias) {
  extern __shared__ unsigned short sm[];   // [buf][op][half][128*64] = 128 KiB
  const int tid = threadIdx.x;
  const int lane = tid & 63;
  const int wv = tid >> 6;
  const int q15 = lane & 15, quad = lane >> 4;
  const int wm = wv >> 2, wn = wv & 3;     // 2 x 4 wave grid; wave tile 128x64
  const int n0 = blockIdx.x * 256, m0 = blockIdx.y * 256;

  f32x4 acc[8][4] = {};
  bf16x8 af[8][2], bfr[4][2];

  // prologue: tile0 (A h0,h1, B h0,h1) -> buf0; tile1 A halves -> buf1
  STAGE8(0, 0, 0, 0); STAGE8(0, 0, 1, 0); STAGE8(0, 1, 0, 0); STAGE8(0, 1, 1, 0);
  STAGE8(1, 0, 0, 1); STAGE8(1, 0, 1, 1);
  asm volatile("s_waitcnt vmcnt(4)" ::: "memory");   // tile0 resident; tile1 A in flight
  __builtin_amdgcn_s_barrier();

  for (int T = 0; T < 32; ++T) {
    const int buf = T & 1;
    // P0: read A0-3, B0-1 (12 x ds_read_b128); stage (T+1) B h0; Q(0,0)
#pragma unroll
    for (int mf = 0; mf < 4; ++mf) { RDA8(af[mf][0], buf, mf, 0); RDA8(af[mf][1], buf, mf, 1); }
#pragma unroll
    for (int nf = 0; nf < 2; ++nf) { RDB8(bfr[nf][0], buf, nf, 0); RDB8(bfr[nf][1], buf, nf, 1); }
    if (T + 1 < 32) STAGE8(buf ^ 1, 1, 0, T + 1);
    MFMA_Q(0, 0);
    // P1: read A4-7, B2-3 (12); stage (T+1) B h1; Q(0,1)
#pragma unroll
    for (int mf = 4; mf < 8; ++mf) { RDA8(af[mf][0], buf, mf, 0); RDA8(af[mf][1], buf, mf, 1); }
#pragma unroll
    for (int nf = 2; nf < 4; ++nf) { RDB8(bfr[nf][0], buf, nf, 0); RDB8(bfr[nf][1], buf, nf, 1); }
    if (T + 1 < 32) STAGE8(buf ^ 1, 1, 1, T + 1);
    MFMA_Q(0, 2);
    // P2: stage (T+2) A h0; Q(1,1)
    if (T + 2 < 32) STAGE8(buf, 0, 0, T + 2);
    MFMA_Q(4, 2);
    // P3: stage (T+2) A h1; counted vmcnt; Q(1,0)
    if (T + 2 < 32) STAGE8(buf, 0, 1, T + 2);
    if (T < 30) { asm volatile("s_waitcnt vmcnt(4)" ::: "memory"); }
    else if (T == 30) { asm volatile("s_waitcnt vmcnt(0)" ::: "memory"); }
    MFMA_Q(4, 0);
  }

  float bv[4];
#pragma unroll
  for (int nf = 0; nf < 4; ++nf) bv[nf] = bias[n0 + wn * 64 + nf * 16 + q15];
#pragma unroll
  for (int mf = 0; mf < 8; ++mf)
#pragma unroll
    for (int nf = 0; nf < 4; ++nf) {
      int col = n0 + wn * 64 + nf * 16 + q15;
      int row = m0 + wm * 128 + mf * 16 + quad * 4;
#pragma unroll
      for (int r = 0; r < 4; ++r)
        outf[(size_t)(row + r) * DIM + col] = acc[mf][nf][r] + bv[nf];
    }
}

// ---------------------------------------------------------------- flash attention (R0 structure, known-good)
// Per bh: t in 0..11. t<8: single q-tile qt=15-t; t>=8: paired {15-t, t-8} = 18 iters.
// 768 blocks = 3 blocks/CU co-resident. 4 waves x 32 q rows, KV tiles of 64,
// St-swap (softmax rows in-register), fixed-max softmax, Q pre-scaled.
// R2 lesson: VGPR-staged async split forced scratch spills (566MB writes,
// MfmaUtil 0.6%). Keep the async16 + __syncthreads structure.
__global__ __launch_bounds__(256) void attn_kernel(
    const unsigned short* __restrict__ Q,    // (B*H, S, HD) rope'd * CS
    const unsigned short* __restrict__ Kg,   // (B*H, S, HD) rope'd
    const unsigned short* __restrict__ Vt,   // (B*H, HD, S)
    unsigned short* __restrict__ O) {        // (B, S, H, HD) bf16
  __shared__ unsigned short Ks[64 * 128];
  __shared__ unsigned short Vs[128 * 64];
  __shared__ unsigned short Ps[4 * 32 * 72];
  const int tid = threadIdx.x;
  const int lane = tid & 63, wv = tid >> 6;
  const int q15 = lane & 15, quad = lane >> 4;
  const int bh = blockIdx.x & 63;
  const int t = blockIdx.x >> 6;             // 0..11
  const int nseg = (t < 8) ? 1 : 2;
  const int b = bh >> 4, h = bh & 15;
  unsigned short* Pw = Ps + wv * (32 * 72);

  for (int seg = 0; seg < nseg; ++seg) {
    const int qt = (t < 8) ? (15 - t) : (seg == 0 ? (15 - t) : (t - 8));
    const int q0w = qt * 128 + wv * 32;

    bf16x8 qf[2][4];
#pragma unroll
    for (int nq = 0; nq < 2; ++nq) {
      const unsigned short* qp = Q + ((size_t)bh * SEQ + q0w + nq * 16 + q15) * HD + quad * 8;
#pragma unroll
      for (int ks = 0; ks < 4; ++ks) qf[nq][ks] = *(const bf16x8*)(qp + ks * 32);
    }

    f32x4 oacc[2][8] = {};
    float rs[2] = {0.f, 0.f};
    const int jmax = 2 * qt + 2;
    const int jcap = 2 * qt + (wv >> 1);

    for (int j = 0; j < jmax; ++j) {
      const int kv0 = j * 64;
      __syncthreads();
#pragma unroll
      for (int i = 0; i < 4; ++i) {
        int l = i * 256 + tid;
        int r = l >> 4, c = (l & 15) ^ (r & 15);
        async16(&Ks[l * 8], Kg + ((size_t)bh * SEQ + kv0 + r) * HD + c * 8);
      }
#pragma unroll
      for (int i = 0; i < 4; ++i) {
        int l = i * 256 + tid;
        int r = l >> 3, c = (l & 7) ^ (r & 7);
        async16(&Vs[l * 8], Vt + ((size_t)bh * HD + r) * SEQ + kv0 + c * 8);
      }
      __syncthreads();

      if (j <= jcap) {
        const bool edge = (j == jcap);
#pragma unroll
        for (int mi = 0; mi < 4; ++mi) {
          f32x4 st[2] = {};
#pragma unroll
          for (int ks = 0; ks < 4; ++ks) {
            int r = mi * 16 + q15;
            int c = ks * 4 + quad;
            bf16x8 kf = *(const bf16x8*)&Ks[(r * 16 + (c ^ (r & 15))) * 8];
#pragma unroll
            for (int nq = 0; nq < 2; ++nq)
              st[nq] = __builtin_amdgcn_mfma_f32_16x16x32_bf16(kf, qf[nq][ks], st[nq], 0, 0, 0);
          }
#pragma unroll
          for (int nq = 0; nq < 2; ++nq) {
            unsigned int u[4];
#pragma unroll
            for (int r = 0; r < 4; ++r) {
              float p = exp2f(st[nq][r]);
              if (edge) {
                int kv = kv0 + mi * 16 + quad * 4 + r;
                int qq = q0w + nq * 16 + q15;
                p = (kv > qq) ? 0.f : p;
              }
              unsigned int uu = __builtin_bit_cast(unsigned int, p) & 0xffff0000u;
              rs[nq] += __builtin_bit_cast(float, uu);
              u[r] = uu;
            }
            uint2 pk;
            pk.x = (u[0] >> 16) | u[1];
            pk.y = (u[2] >> 16) | u[3];
            *(uint2*)&Pw[(nq * 16 + q15) * 72 + mi * 16 + quad * 4] = pk;
          }
        }
#pragma unroll
        for (int ks = 0; ks < 2; ++ks) {
          bf16x8 pf[2];
#pragma unroll
          for (int mq = 0; mq < 2; ++mq)
            pf[mq] = *(const bf16x8*)&Pw[(mq * 16 + q15) * 72 + ks * 32 + quad * 8];
#pragma unroll
          for (int nf = 0; nf < 8; ++nf) {
            int r = nf * 16 + q15;
            int c = ks * 4 + quad;
            bf16x8 vf = *(const bf16x8*)&Vs[(r * 8 + (c ^ (r & 7))) * 8];
#pragma unroll
            for (int mq = 0; mq < 2; ++mq)
              oacc[mq][nf] = __builtin_amdgcn_mfma_f32_16x16x32_bf16(pf[mq], vf, oacc[mq][nf], 0, 0, 0);
          }
        }
      }
    }

    // segment epilogue: reduce row sums across quads, write O
#pragma unroll
    for (int nq = 0; nq < 2; ++nq) {
      rs[nq] += __shfl_xor(rs[nq], 16);
      rs[nq] += __shfl_xor(rs[nq], 32);
    }
#pragma unroll
    for (int mq = 0; mq < 2; ++mq) {
#pragma unroll
      for (int r = 0; r < 4; ++r) {
        float l = __shfl(rs[mq], quad * 4 + r);
        float inv = 1.0f / l;
        int qq = q0w + mq * 16 + quad * 4 + r;
        size_t base = (((size_t)b * SEQ + qq) * NH + h) * HD;
#pragma unroll
        for (int nf = 0; nf < 8; ++nf)
          O[base + nf * 16 + q15] = f2bf(oacc[mq][nf][r] * inv);
      }
    }
  }
}

// ---------------------------------------------------------------- launch
extern "C" void kernel_launch(void* const* d_in, const int* in_sizes, int n_in,
                              void* d_out, int out_size, void* d_ws, size_t ws_size,
                              hipStream_t stream) {
  (void)in_sizes; (void)n_in; (void)out_size; (void)ws_size;
  const float* x  = (const float*)d_in[0];
  const float* Wq = (const float*)d_in[1];
  const float* Wk = (const float*)d_in[2];
  const float* Wv = (const float*)d_in[3];
  const float* Wo = (const float*)d_in[4];
  const float* bo = (const float*)d_in[5];
  float* out = (float*)d_out;

  const size_t XE = (size_t)BATCH * SEQ * DIM;   // 16.7M elems
  const size_t WE = (size_t)DIM * DIM;           // 4.2M elems

  char* p = (char*)d_ws;
  unsigned short* xb   = (unsigned short*)p; p += XE * 2;
  unsigned short* Wall = (unsigned short*)p; p += 4 * WE * 2;
  unsigned short* Qg   = (unsigned short*)p; p += XE * 2;
  unsigned short* Kb   = (unsigned short*)p; p += XE * 2;
  unsigned short* Vtb  = (unsigned short*)p; p += XE * 2;
  unsigned short* attn = (unsigned short*)p; p += XE * 2;

  static bool attr_set = false;
  if (!attr_set) {
    hipFuncSetAttribute((const void*)gemm_out,
                        hipFuncAttributeMaxDynamicSharedMemorySize, 131072);
    attr_set = true;
  }

  cast_all_kernel<<<(int)(2 * XE / 4 / 256), 256, 0, stream>>>(x, Wq, Wk, Wv, Wo, xb);

  gemm_qkv<<<dim3(48, 64), 256, 0, stream>>>(
      xb, Wall, Wall + WE, Wall + 2 * WE, Qg, Kb, Vtb);

  attn_kernel<<<dim3(768), 256, 0, stream>>>(Qg, Kb, Vtb, attn);

  gemm_out<<<dim3(DIM / 256, (BATCH * SEQ) / 256), 512, 131072, stream>>>(
      attn, Wall + 3 * WE, out, bo);
}